// Round 12
// baseline (1973.269 us; speedup 1.0000x reference)
//
#include <hip/hip_runtime.h>
#include <cmath>

// GRU scan, T=128 B=512 D=H=512, split-f16 MFMA (f32-accurate):
//   v = hi + lo/2048 ; a*b ~= ah*bh + (ah*bl + al*bh)/2048
// Phase 0: conv_w (weights -> K-major split planes in ws).
// Phase 1 per chunk: fsplit(x); gi = x@Wi + bi (round-7 GEMM, 202us measured).
// Phase 2: 128 per-step kernels, TWO barriers total:
//   4 waves = (jh, kh): kh = K-half split. A (h) staged once full-K into LDS
//   [32][520]; B weights direct-global 3-deep ring; 144 MFMA burst per wave;
//   K-half partials reduced via LDS; kh=0 waves do the gate epilogue.
// d_out = [hT (B*H) | ys (T*B*H)]; h_prev for step t read from ys[t-1].

#define T_STEPS 128
#define B_SZ 512
#define HD 512

typedef __attribute__((ext_vector_type(8))) _Float16 f16x8;
typedef __attribute__((ext_vector_type(4))) float f32x4;

#define MFMA16(a, b, c) __builtin_amdgcn_mfma_f32_16x16x32_f16((a), (b), (c), 0, 0, 0)

__device__ __forceinline__ float sigf_(float x) { return 1.0f / (1.0f + __expf(-x)); }
__device__ __forceinline__ float tanhf_(float x) { return 1.0f - 2.0f / (__expf(2.0f * x) + 1.0f); }

// ---------------------------------------------------------------------------
// Phase 0: transpose + split weights. WT[n][k]: n<1536 -> Wi col n;
// n>=1536: m=n-1536, g=m>>9, c=m&511: g<2 -> Wh_rz[k][g*512+c]; g==2 -> Wh_n[k][c]
// ---------------------------------------------------------------------------
__global__ __launch_bounds__(256) void conv_w(
    const float* __restrict__ Wi, const float* __restrict__ Wh_rz,
    const float* __restrict__ Wh_n,
    _Float16* __restrict__ WT_hi, _Float16* __restrict__ WT_lo)
{
    __shared__ float Tl[64][65];
    const int tid = threadIdx.x;
    const int k0 = blockIdx.x * 64;
    const int n0 = blockIdx.y * 64;

    const float* base;
    int stride;
    if (n0 < 1536) { base = Wi + n0; stride = 1536; }
    else {
        int m = n0 - 1536, g = m >> 9, c = m & 511;
        if (g < 2) { base = Wh_rz + g * 512 + c; stride = 1024; }
        else       { base = Wh_n + c;            stride = 512; }
    }

    #pragma unroll
    for (int p = 0; p < 4; ++p) {
        int kr = p * 16 + (tid >> 4);
        int nc = (tid & 15) * 4;
        float4 v = *(const float4*)(base + (size_t)(k0 + kr) * stride + nc);
        Tl[kr][nc + 0] = v.x; Tl[kr][nc + 1] = v.y;
        Tl[kr][nc + 2] = v.z; Tl[kr][nc + 3] = v.w;
    }
    __syncthreads();

    const int nr  = tid >> 2;
    const int kc0 = (tid & 3) * 16;
    f16x8 h0v, h1v, l0v, l1v;
    #pragma unroll
    for (int j = 0; j < 16; ++j) {
        float v = Tl[kc0 + j][nr];
        _Float16 th = (_Float16)v;
        _Float16 tl = (_Float16)((v - (float)th) * 2048.0f);
        if (j < 8) { h0v[j] = th; l0v[j] = tl; }
        else       { h1v[j - 8] = th; l1v[j - 8] = tl; }
    }
    size_t o = (size_t)(n0 + nr) * 512 + k0 + kc0;
    *(f16x8*)(WT_hi + o)     = h0v;
    *(f16x8*)(WT_hi + o + 8) = h1v;
    *(f16x8*)(WT_lo + o)     = l0v;
    *(f16x8*)(WT_lo + o + 8) = l1v;
}

// ---------------------------------------------------------------------------
// fsplit: linear f32 -> split f16 planes. n8 = elems/8.
// ---------------------------------------------------------------------------
__global__ __launch_bounds__(256) void fsplit(
    const float* __restrict__ src,
    _Float16* __restrict__ hi, _Float16* __restrict__ lo, int n8)
{
    const int stride = gridDim.x * 256;
    for (int g = blockIdx.x * 256 + threadIdx.x; g < n8; g += stride) {
        const float* p = src + (size_t)g * 8;
        float4 v0 = *(const float4*)p;
        float4 v1 = *(const float4*)(p + 4);
        float f[8] = {v0.x, v0.y, v0.z, v0.w, v1.x, v1.y, v1.z, v1.w};
        f16x8 hh, ll;
        #pragma unroll
        for (int q = 0; q < 8; ++q) {
            _Float16 th = (_Float16)f[q];
            hh[q] = th;
            ll[q] = (_Float16)((f[q] - (float)th) * 2048.0f);
        }
        *(f16x8*)(hi + (size_t)g * 8) = hh;
        *(f16x8*)(lo + (size_t)g * 8) = ll;
    }
}

// ---------------------------------------------------------------------------
// Phase 1: gi = x @ Wi + bi. Tile 128m x 64n, BK=64, 8 stages, 4 waves.
// LDS [row][72] halfs. Reg-staged plane copies; next-stage global prefetch.
// grid (24 n-tiles fastest, R/128 m).  [round-7 kernel, 202 us measured]
// ---------------------------------------------------------------------------
__global__ __launch_bounds__(256, 1) void gi_gemm(
    const _Float16* __restrict__ XT_hi, const _Float16* __restrict__ XT_lo,
    const _Float16* __restrict__ WT_hi, const _Float16* __restrict__ WT_lo,
    const float* __restrict__ bi,
    float* __restrict__ gi)
{
    __shared__ __align__(16) _Float16 Ah[128 * 72];
    __shared__ __align__(16) _Float16 Al[128 * 72];
    __shared__ __align__(16) _Float16 Bh[64 * 72];
    __shared__ __align__(16) _Float16 Bl[64 * 72];

    const int tid = threadIdx.x;
    const int n0 = blockIdx.x * 64;
    const int m0 = blockIdx.y * 128;
    const int l = tid & 63, w = tid >> 6;
    const int lr = l & 15, lkq = l >> 4, lk = lkq * 8;

    const int aRow[4] = { (tid + 0) >> 3, (tid + 256) >> 3, (tid + 512) >> 3, (tid + 768) >> 3 };
    const int aOff = (tid & 7) * 8;

    f16x8 rAh[4], rAl[4], rBh[2], rBl[2];
    #pragma unroll
    for (int i = 0; i < 4; ++i) {
        const size_t g = (size_t)(m0 + aRow[i]) * 512 + aOff;
        rAh[i] = *(const f16x8*)(XT_hi + g);
        rAl[i] = *(const f16x8*)(XT_lo + g);
    }
    #pragma unroll
    for (int i = 0; i < 2; ++i) {
        const size_t g = (size_t)(n0 + aRow[i]) * 512 + aOff;
        rBh[i] = *(const f16x8*)(WT_hi + g);
        rBl[i] = *(const f16x8*)(WT_lo + g);
    }

    f32x4 am[2][4], acr[2][4];
    #pragma unroll
    for (int fm = 0; fm < 2; ++fm)
        #pragma unroll
        for (int fn = 0; fn < 4; ++fn) {
            am[fm][fn] = (f32x4){0, 0, 0, 0};
            acr[fm][fn] = (f32x4){0, 0, 0, 0};
        }

    for (int s = 0; s < 8; ++s) {
        __syncthreads();
        #pragma unroll
        for (int i = 0; i < 4; ++i) {
            *(f16x8*)&Ah[aRow[i] * 72 + aOff] = rAh[i];
            *(f16x8*)&Al[aRow[i] * 72 + aOff] = rAl[i];
        }
        #pragma unroll
        for (int i = 0; i < 2; ++i) {
            *(f16x8*)&Bh[aRow[i] * 72 + aOff] = rBh[i];
            *(f16x8*)&Bl[aRow[i] * 72 + aOff] = rBl[i];
        }
        __syncthreads();

        if (s < 7) {
            const int k0 = (s + 1) * 64;
            #pragma unroll
            for (int i = 0; i < 4; ++i) {
                const size_t g = (size_t)(m0 + aRow[i]) * 512 + k0 + aOff;
                rAh[i] = *(const f16x8*)(XT_hi + g);
                rAl[i] = *(const f16x8*)(XT_lo + g);
            }
            #pragma unroll
            for (int i = 0; i < 2; ++i) {
                const size_t g = (size_t)(n0 + aRow[i]) * 512 + k0 + aOff;
                rBh[i] = *(const f16x8*)(WT_hi + g);
                rBl[i] = *(const f16x8*)(WT_lo + g);
            }
        }

        #pragma unroll
        for (int kk = 0; kk < 2; ++kk) {
            const int ko = kk * 32 + lk;
            f16x8 ah[2], al[2], bh[4], bl[4];
            #pragma unroll
            for (int fm = 0; fm < 2; ++fm) {
                ah[fm] = *(const f16x8*)&Ah[(w * 32 + fm * 16 + lr) * 72 + ko];
                al[fm] = *(const f16x8*)&Al[(w * 32 + fm * 16 + lr) * 72 + ko];
            }
            #pragma unroll
            for (int fn = 0; fn < 4; ++fn) {
                bh[fn] = *(const f16x8*)&Bh[(fn * 16 + lr) * 72 + ko];
                bl[fn] = *(const f16x8*)&Bl[(fn * 16 + lr) * 72 + ko];
            }
            #pragma unroll
            for (int fm = 0; fm < 2; ++fm)
                #pragma unroll
                for (int fn = 0; fn < 4; ++fn) {
                    am[fm][fn]  = MFMA16(ah[fm], bh[fn], am[fm][fn]);
                    acr[fm][fn] = MFMA16(ah[fm], bl[fn], acr[fm][fn]);
                    acr[fm][fn] = MFMA16(al[fm], bh[fn], acr[fm][fn]);
                }
        }
    }

    const float inv = 1.0f / 2048.0f;
    #pragma unroll
    for (int fn = 0; fn < 4; ++fn) {
        const int col = n0 + fn * 16 + lr;
        const float bv = bi[col];
        #pragma unroll
        for (int fm = 0; fm < 2; ++fm)
            #pragma unroll
            for (int i = 0; i < 4; ++i) {
                const int row = m0 + w * 32 + fm * 16 + lkq * 4 + i;
                gi[(size_t)row * 1536 + col] =
                    am[fm][fn][i] + acr[fm][fn][i] * inv + bv;
            }
    }
}

// ---------------------------------------------------------------------------
// Phase 2: step kernel, K-split-across-waves, 2 barriers total.
// Tile 32m x 32j x 3 gates, grid (16 j, 16 m). 4 waves = (jh = w&1, kh = w>>1).
// Wave (jh,kh): all 32 m-rows x 16 j-cols over K in [kh*256,(kh+1)*256):
//   8 kk x 2 fm x 9 MFMA. A staged once (full K) in LDS [32][520]; B weights
//   direct-global, 3-deep ring. K-half partials reduced via LDS; kh=0 waves
//   run the gate epilogue.
// ---------------------------------------------------------------------------
__global__ __launch_bounds__(256, 1) void gru_step_h(
    const int*   __restrict__ rst,      // [B]
    const float* __restrict__ hsrc,     // [B][512]
    const _Float16* __restrict__ WT_hi, // hidden rows at 1536+
    const _Float16* __restrict__ WT_lo,
    const float* __restrict__ gi_t,     // [512][1536] (bi folded in)
    const float* __restrict__ bh_n,     // [512]
    float* __restrict__ hdst,
    float* __restrict__ hT_out)
{
    __shared__ __align__(16) _Float16 Ah[32 * 520];
    __shared__ __align__(16) _Float16 Al[32 * 520];
    __shared__ __align__(16) float Red[2][64][52];   // kh=1 partials

    const int tid = threadIdx.x;
    const int j0 = blockIdx.x * 32;
    const int m0 = blockIdx.y * 32;
    const int l = tid & 63, w = tid >> 6;
    const int jh = w & 1, kh = w >> 1;
    const int lr = l & 15, lkq = l >> 4, lk = lkq * 8;
    const int j = j0 + jh * 16 + lr;

    // ---- B ring preload (deepest-latency loads issued first) ----
    const _Float16* bh_p = WT_hi + (size_t)(1536 + j) * 512 + kh * 256 + lk;
    const _Float16* bl_p = WT_lo + (size_t)(1536 + j) * 512 + kh * 256 + lk;
    constexpr size_t GS = (size_t)512 * 512;
    f16x8 ring[3][6];
    #pragma unroll
    for (int d = 0; d < 3; ++d) {
        const int o = d * 32;
        ring[d][0] = *(const f16x8*)(bh_p + o);
        ring[d][1] = *(const f16x8*)(bh_p + GS + o);
        ring[d][2] = *(const f16x8*)(bh_p + 2 * GS + o);
        ring[d][3] = *(const f16x8*)(bl_p + o);
        ring[d][4] = *(const f16x8*)(bl_p + GS + o);
        ring[d][5] = *(const f16x8*)(bl_p + 2 * GS + o);
    }

    // ---- epilogue operand prefetch (kh==0 waves only) ----
    float gi_pre[3][2][4], h_pre[2][4];
    if (kh == 0) {
        #pragma unroll
        for (int fm = 0; fm < 2; ++fm)
            #pragma unroll
            for (int i = 0; i < 4; ++i) {
                const int row = m0 + fm * 16 + lkq * 4 + i;
                const size_t gb = (size_t)row * 1536 + j;
                gi_pre[0][fm][i] = gi_t[gb];
                gi_pre[1][fm][i] = gi_t[gb + 512];
                gi_pre[2][fm][i] = gi_t[gb + 1024];
                h_pre[fm][i] = hsrc[(size_t)row * 512 + j];
            }
    }

    // ---- stage h rows m0..m0+31 (f32 -> split f16, reset-masked), full K ----
    {
        const int srow  = tid >> 3;        // 0..31
        const int scol0 = (tid & 7) * 8;
        const bool smask = (rst[m0 + srow] != 0);
        const float* hp = hsrc + (size_t)(m0 + srow) * 512;
        #pragma unroll
        for (int c = 0; c < 8; ++c) {
            const int col = c * 64 + scol0;
            float4 v0 = *(const float4*)(hp + col);
            float4 v1 = *(const float4*)(hp + col + 4);
            if (smask) { v0 = make_float4(0,0,0,0); v1 = make_float4(0,0,0,0); }
            float f[8] = {v0.x, v0.y, v0.z, v0.w, v1.x, v1.y, v1.z, v1.w};
            f16x8 hh, ll;
            #pragma unroll
            for (int q = 0; q < 8; ++q) {
                float v = f[q];
                _Float16 th = (_Float16)v;
                hh[q] = th; ll[q] = (_Float16)((v - (float)th) * 2048.0f);
            }
            *(f16x8*)&Ah[srow * 520 + col] = hh;
            *(f16x8*)&Al[srow * 520 + col] = ll;
        }
    }
    __syncthreads();   // barrier 1: A staged

    // ---- MFMA burst: 8 kk x 2 fm x 9 MFMA ----
    f32x4 am[2][3], acr[2][3];
    #pragma unroll
    for (int fm = 0; fm < 2; ++fm)
        #pragma unroll
        for (int g = 0; g < 3; ++g) {
            am[fm][g] = (f32x4){0,0,0,0};
            acr[fm][g] = (f32x4){0,0,0,0};
        }

    const int koBase = kh * 256;
    #pragma unroll
    for (int kk = 0; kk < 8; ++kk) {
        const int s = kk % 3;
        #pragma unroll
        for (int fm = 0; fm < 2; ++fm) {
            const int ar = (fm * 16 + lr) * 520 + koBase + kk * 32 + lk;
            f16x8 ah = *(const f16x8*)&Ah[ar];
            f16x8 al = *(const f16x8*)&Al[ar];
            am[fm][0]  = MFMA16(ah, ring[s][0], am[fm][0]);
            acr[fm][0] = MFMA16(ah, ring[s][3], acr[fm][0]);
            acr[fm][0] = MFMA16(al, ring[s][0], acr[fm][0]);
            am[fm][1]  = MFMA16(ah, ring[s][1], am[fm][1]);
            acr[fm][1] = MFMA16(ah, ring[s][4], acr[fm][1]);
            acr[fm][1] = MFMA16(al, ring[s][1], acr[fm][1]);
            am[fm][2]  = MFMA16(ah, ring[s][2], am[fm][2]);
            acr[fm][2] = MFMA16(ah, ring[s][5], acr[fm][2]);
            acr[fm][2] = MFMA16(al, ring[s][2], acr[fm][2]);
        }
        if (kk < 5) {
            const int o = (kk + 3) * 32;
            ring[s][0] = *(const f16x8*)(bh_p + o);
            ring[s][1] = *(const f16x8*)(bh_p + GS + o);
            ring[s][2] = *(const f16x8*)(bh_p + 2 * GS + o);
            ring[s][3] = *(const f16x8*)(bl_p + o);
            ring[s][4] = *(const f16x8*)(bl_p + GS + o);
            ring[s][5] = *(const f16x8*)(bl_p + 2 * GS + o);
        }
    }

    // ---- K-half reduction ----
    if (kh == 1) {
        float* dst = &Red[jh][l][0];
        #pragma unroll
        for (int fm = 0; fm < 2; ++fm)
            #pragma unroll
            for (int g = 0; g < 3; ++g) {
                const int q = fm * 3 + g;
                *(f32x4*)&dst[q * 4]      = am[fm][g];
                *(f32x4*)&dst[24 + q * 4] = acr[fm][g];
            }
    }
    __syncthreads();   // barrier 2: partials visible

    if (kh == 0) {
        const float* src = &Red[jh][l][0];
        #pragma unroll
        for (int fm = 0; fm < 2; ++fm)
            #pragma unroll
            for (int g = 0; g < 3; ++g) {
                const int q = fm * 3 + g;
                f32x4 pm = *(const f32x4*)&src[q * 4];
                f32x4 pc = *(const f32x4*)&src[24 + q * 4];
                am[fm][g] += pm;
                acr[fm][g] += pc;
            }

        // ---- epilogue: gates ----
        const float bhn = bh_n[j];
        const float inv = 1.0f / 2048.0f;
        #pragma unroll
        for (int fm = 0; fm < 2; ++fm)
            #pragma unroll
            for (int i = 0; i < 4; ++i) {
                const int row = m0 + fm * 16 + lkq * 4 + i;
                const bool rm = (rst[row] != 0);
                const float heff = rm ? 0.f : h_pre[fm][i];
                const float r = sigf_(gi_pre[0][fm][i] + am[fm][0][i] + acr[fm][0][i] * inv);
                const float z = sigf_(gi_pre[1][fm][i] + am[fm][1][i] + acr[fm][1][i] * inv);
                const float n = tanhf_(gi_pre[2][fm][i]
                                       + r * (am[fm][2][i] + acr[fm][2][i] * inv + bhn));
                const float hv = (1.f - z) * n + z * heff;
                hdst[(size_t)row * 512 + j] = hv;
                if (hT_out) hT_out[(size_t)row * 512 + j] = hv;
            }
    }
}

// ---------------------------------------------------------------------------
// Fallback: pure-f32 step kernel (only if d_ws too small).
// ---------------------------------------------------------------------------
constexpr int BM_F = 32, BN_F = 32, BK_F = 32;
constexpr int LDT = BM_F + 4;

__global__ __launch_bounds__(256, 1) void gru_step_f32(
    const float* __restrict__ x, const int* __restrict__ rst,
    const float* __restrict__ h_prev, const float* __restrict__ Wi,
    const float* __restrict__ bi, const float* __restrict__ Wh_rz,
    const float* __restrict__ Wh_n, const float* __restrict__ bh_n,
    float* __restrict__ h_out, float* __restrict__ hT_out)
{
    __shared__ float xs[BK_F][LDT];
    __shared__ float hs[BK_F][LDT];
    __shared__ float wt[6][BK_F][LDT];

    const int tid = threadIdx.x;
    const int bm0 = blockIdx.x * BM_F;
    const int jn0 = blockIdx.y * BN_F;
    const int lrw = tid >> 3;
    const int lcw = (tid & 7) << 2;
    const int ty = tid >> 4, tx = tid & 15;
    const int row0 = 2 * ty, col0 = 2 * tx;

    float aR[2][2] = {{0,0},{0,0}}, aZ[2][2] = {{0,0},{0,0}}, aN[2][2] = {{0,0},{0,0}};
    float hR[2][2] = {{0,0},{0,0}}, hZ[2][2] = {{0,0},{0,0}}, hN[2][2] = {{0,0},{0,0}};

    const int ldrow = bm0 + lrw;
    const bool rmaskld = (rst[ldrow] != 0);
    const float* xrow = x + (size_t)ldrow * 512;
    const float* hrow = h_prev + (size_t)ldrow * 512;

    for (int k0 = 0; k0 < 512; k0 += BK_F) {
        float4 xv = *(const float4*)(xrow + k0 + lcw);
        float4 hv = *(const float4*)(hrow + k0 + lcw);
        if (rmaskld) { hv.x = hv.y = hv.z = hv.w = 0.f; }
        const float* wi_row = Wi + (size_t)(k0 + lrw) * 1536;
        const float* wh_row = Wh_rz + (size_t)(k0 + lrw) * 1024;
        float4 w0v = *(const float4*)(wi_row + jn0 + lcw);
        float4 w1v = *(const float4*)(wi_row + 512 + jn0 + lcw);
        float4 w2v = *(const float4*)(wi_row + 1024 + jn0 + lcw);
        float4 w3v = *(const float4*)(wh_row + jn0 + lcw);
        float4 w4v = *(const float4*)(wh_row + 512 + jn0 + lcw);
        float4 w5v = *(const float4*)(Wh_n + (size_t)(k0 + lrw) * 512 + jn0 + lcw);
        __syncthreads();
        xs[lcw+0][lrw]=xv.x; xs[lcw+1][lrw]=xv.y; xs[lcw+2][lrw]=xv.z; xs[lcw+3][lrw]=xv.w;
        hs[lcw+0][lrw]=hv.x; hs[lcw+1][lrw]=hv.y; hs[lcw+2][lrw]=hv.z; hs[lcw+3][lrw]=hv.w;
        *(float4*)&wt[0][lrw][lcw] = w0v; *(float4*)&wt[1][lrw][lcw] = w1v;
        *(float4*)&wt[2][lrw][lcw] = w2v; *(float4*)&wt[3][lrw][lcw] = w3v;
        *(float4*)&wt[4][lrw][lcw] = w4v; *(float4*)&wt[5][lrw][lcw] = w5v;
        __syncthreads();
        #pragma unroll
        for (int kk = 0; kk < BK_F; ++kk) {
            float2 xa = *(const float2*)&xs[kk][row0];
            float2 ha = *(const float2*)&hs[kk][row0];
            float2 w0 = *(const float2*)&wt[0][kk][col0];
            float2 w1 = *(const float2*)&wt[1][kk][col0];
            float2 w2 = *(const float2*)&wt[2][kk][col0];
            float2 w3 = *(const float2*)&wt[3][kk][col0];
            float2 w4 = *(const float2*)&wt[4][kk][col0];
            float2 w5 = *(const float2*)&wt[5][kk][col0];
            aR[0][0]=fmaf(xa.x,w0.x,aR[0][0]); aR[0][1]=fmaf(xa.x,w0.y,aR[0][1]);
            aR[1][0]=fmaf(xa.y,w0.x,aR[1][0]); aR[1][1]=fmaf(xa.y,w0.y,aR[1][1]);
            aZ[0][0]=fmaf(xa.x,w1.x,aZ[0][0]); aZ[0][1]=fmaf(xa.x,w1.y,aZ[0][1]);
            aZ[1][0]=fmaf(xa.y,w1.x,aZ[1][0]); aZ[1][1]=fmaf(xa.y,w1.y,aZ[1][1]);
            aN[0][0]=fmaf(xa.x,w2.x,aN[0][0]); aN[0][1]=fmaf(xa.x,w2.y,aN[0][1]);
            aN[1][0]=fmaf(xa.y,w2.x,aN[1][0]); aN[1][1]=fmaf(xa.y,w2.y,aN[1][1]);
            hR[0][0]=fmaf(ha.x,w3.x,hR[0][0]); hR[0][1]=fmaf(ha.x,w3.y,hR[0][1]);
            hR[1][0]=fmaf(ha.y,w3.x,hR[1][0]); hR[1][1]=fmaf(ha.y,w3.y,hR[1][1]);
            hZ[0][0]=fmaf(ha.x,w4.x,hZ[0][0]); hZ[0][1]=fmaf(ha.x,w4.y,hZ[0][1]);
            hZ[1][0]=fmaf(ha.y,w4.x,hZ[1][0]); hZ[1][1]=fmaf(ha.y,w4.y,hZ[1][1]);
            hN[0][0]=fmaf(ha.x,w5.x,hN[0][0]); hN[0][1]=fmaf(ha.x,w5.y,hN[0][1]);
            hN[1][0]=fmaf(ha.y,w5.x,hN[1][0]); hN[1][1]=fmaf(ha.y,w5.y,hN[1][1]);
        }
    }
    #pragma unroll
    for (int ii = 0; ii < 2; ++ii) {
        const int b = bm0 + row0 + ii;
        const bool rm = (rst[b] != 0);
        #pragma unroll
        for (int jj = 0; jj < 2; ++jj) {
            const int jn = jn0 + col0 + jj;
            const float heff = rm ? 0.f : h_prev[(size_t)b * 512 + jn];
            const float r = sigf_(aR[ii][jj] + bi[jn] + hR[ii][jj]);
            const float z = sigf_(aZ[ii][jj] + bi[512 + jn] + hZ[ii][jj]);
            const float n = tanhf(aN[ii][jj] + bi[1024 + jn] + r * (hN[ii][jj] + bh_n[jn]));
            const float v = (1.f - z) * n + z * heff;
            h_out[(size_t)b * 512 + jn] = v;
            if (hT_out) hT_out[(size_t)b * 512 + jn] = v;
        }
    }
}

// ---------------------------------------------------------------------------
extern "C" void kernel_launch(void* const* d_in, const int* in_sizes, int n_in,
                              void* d_out, int out_size, void* d_ws, size_t ws_size,
                              hipStream_t stream) {
    const float* h0     = (const float*)d_in[0];
    const float* ins    = (const float*)d_in[1];
    const int*   resets = (const int*)  d_in[2];
    const float* Wi     = (const float*)d_in[3];
    const float* bi     = (const float*)d_in[4];
    const float* Wh_rz  = (const float*)d_in[5];
    const float* Wh_n   = (const float*)d_in[6];
    const float* bh_n   = (const float*)d_in[7];

    float* out = (float*)d_out;
    float* hT  = out;
    float* ys  = out + (size_t)B_SZ * HD;

    const size_t WPLANE = (size_t)3072 * 512;
    const size_t HP     = (size_t)512 * 512;
    const size_t wbytes = WPLANE * 2 * sizeof(_Float16);   // 6.3 MB

    int CH = 0;
    const int cands[8] = {128, 64, 32, 16, 8, 4, 2, 1};
    for (int c = 0; c < 8; ++c) {
        const size_t xt = (size_t)cands[c] * HP * 2 * sizeof(_Float16);
        const size_t gb = (size_t)cands[c] * 512 * 1536 * sizeof(float);
        if (ws_size >= wbytes + xt + gb) { CH = cands[c]; break; }
    }

    if (CH > 0) {
        char* p = (char*)d_ws;
        _Float16* WT_hi = (_Float16*)p;  p += WPLANE * 2;
        _Float16* WT_lo = (_Float16*)p;  p += WPLANE * 2;
        _Float16* XT_hi = (_Float16*)p;  p += (size_t)CH * HP * 2;
        _Float16* XT_lo = (_Float16*)p;  p += (size_t)CH * HP * 2;
        float* gi = (float*)p;

        conv_w<<<dim3(8, 48), 256, 0, stream>>>(Wi, Wh_rz, Wh_n, WT_hi, WT_lo);

        for (int t0 = 0; t0 < T_STEPS; t0 += CH) {
            const int n8 = CH * (int)(HP / 8);
            int sgrid = (n8 + 255) / 256; if (sgrid > 4096) sgrid = 4096;
            fsplit<<<sgrid, 256, 0, stream>>>(
                ins + (size_t)t0 * HP, XT_hi, XT_lo, n8);
            gi_gemm<<<dim3(24, CH * 4), 256, 0, stream>>>(
                XT_hi, XT_lo, WT_hi, WT_lo, bi, gi);
            for (int t = t0; t < t0 + CH; ++t) {
                const float* hp = (t == 0) ? h0 : (ys + (size_t)(t - 1) * HP);
                float* ho = ys + (size_t)t * HP;
                gru_step_h<<<dim3(16, 16), 256, 0, stream>>>(
                    resets + (size_t)t * 512, hp, WT_hi, WT_lo,
                    gi + (size_t)(t - t0) * 512 * 1536,
                    bh_n, ho, (t == T_STEPS - 1) ? hT : nullptr);
            }
        }
    } else {
        dim3 grid(B_SZ / BM_F, HD / BN_F);
        for (int t = 0; t < T_STEPS; ++t) {
            const float* hp = (t == 0) ? h0 : (ys + (size_t)(t - 1) * HP);
            float* ho = ys + (size_t)t * HP;
            gru_step_f32<<<grid, 256, 0, stream>>>(
                ins + (size_t)t * HP, resets + (size_t)t * 512,
                hp, Wi, bi, Wh_rz, Wh_n, bh_n,
                ho, (t == T_STEPS - 1) ? hT : nullptr);
        }
    }
}

// Round 13
// 1945.593 us; speedup vs baseline: 1.0142x; 1.0142x over previous
//
#include <hip/hip_runtime.h>
#include <cmath>

// GRU scan, T=128 B=512 D=H=512, split-f16 MFMA (f32-accurate):
//   v = hi + lo/2048 ; a*b ~= ah*bh + (ah*bl + al*bh)/2048
// Phase 0: conv_w (weights -> K-major split planes in ws).
// Phase 1 per chunk: fsplit(x); gi = x@Wi + bi (double-buffered LDS GEMM).
// Phase 2: 128 per-step kernels (R11 structure + double-buffered stages):
//   32m x 32j x 3 gates, grid (16,16), 4 waves; h f32->split inline; operands
//   through LDS stride-72; 8 stages, ONE barrier each (dbuf), global prefetch
//   issued post-barrier, LDS write post-compute into the other buffer.
// d_out = [hT (B*H) | ys (T*B*H)]; h_prev for step t read from ys[t-1].

#define T_STEPS 128
#define B_SZ 512
#define HD 512

typedef __attribute__((ext_vector_type(8))) _Float16 f16x8;
typedef __attribute__((ext_vector_type(4))) float f32x4;

#define MFMA16(a, b, c) __builtin_amdgcn_mfma_f32_16x16x32_f16((a), (b), (c), 0, 0, 0)

__device__ __forceinline__ float sigf_(float x) { return 1.0f / (1.0f + __expf(-x)); }
__device__ __forceinline__ float tanhf_(float x) { return 1.0f - 2.0f / (__expf(2.0f * x) + 1.0f); }

// ---------------------------------------------------------------------------
// Phase 0: transpose + split weights. WT[n][k]: n<1536 -> Wi col n;
// n>=1536: m=n-1536, g=m>>9, c=m&511: g<2 -> Wh_rz[k][g*512+c]; g==2 -> Wh_n[k][c]
// ---------------------------------------------------------------------------
__global__ __launch_bounds__(256) void conv_w(
    const float* __restrict__ Wi, const float* __restrict__ Wh_rz,
    const float* __restrict__ Wh_n,
    _Float16* __restrict__ WT_hi, _Float16* __restrict__ WT_lo)
{
    __shared__ float Tl[64][65];
    const int tid = threadIdx.x;
    const int k0 = blockIdx.x * 64;
    const int n0 = blockIdx.y * 64;

    const float* base;
    int stride;
    if (n0 < 1536) { base = Wi + n0; stride = 1536; }
    else {
        int m = n0 - 1536, g = m >> 9, c = m & 511;
        if (g < 2) { base = Wh_rz + g * 512 + c; stride = 1024; }
        else       { base = Wh_n + c;            stride = 512; }
    }

    #pragma unroll
    for (int p = 0; p < 4; ++p) {
        int kr = p * 16 + (tid >> 4);
        int nc = (tid & 15) * 4;
        float4 v = *(const float4*)(base + (size_t)(k0 + kr) * stride + nc);
        Tl[kr][nc + 0] = v.x; Tl[kr][nc + 1] = v.y;
        Tl[kr][nc + 2] = v.z; Tl[kr][nc + 3] = v.w;
    }
    __syncthreads();

    const int nr  = tid >> 2;
    const int kc0 = (tid & 3) * 16;
    f16x8 h0v, h1v, l0v, l1v;
    #pragma unroll
    for (int j = 0; j < 16; ++j) {
        float v = Tl[kc0 + j][nr];
        _Float16 th = (_Float16)v;
        _Float16 tl = (_Float16)((v - (float)th) * 2048.0f);
        if (j < 8) { h0v[j] = th; l0v[j] = tl; }
        else       { h1v[j - 8] = th; l1v[j - 8] = tl; }
    }
    size_t o = (size_t)(n0 + nr) * 512 + k0 + kc0;
    *(f16x8*)(WT_hi + o)     = h0v;
    *(f16x8*)(WT_hi + o + 8) = h1v;
    *(f16x8*)(WT_lo + o)     = l0v;
    *(f16x8*)(WT_lo + o + 8) = l1v;
}

// ---------------------------------------------------------------------------
// fsplit: linear f32 -> split f16 planes. n8 = elems/8.
// ---------------------------------------------------------------------------
__global__ __launch_bounds__(256) void fsplit(
    const float* __restrict__ src,
    _Float16* __restrict__ hi, _Float16* __restrict__ lo, int n8)
{
    const int stride = gridDim.x * 256;
    for (int g = blockIdx.x * 256 + threadIdx.x; g < n8; g += stride) {
        const float* p = src + (size_t)g * 8;
        float4 v0 = *(const float4*)p;
        float4 v1 = *(const float4*)(p + 4);
        float f[8] = {v0.x, v0.y, v0.z, v0.w, v1.x, v1.y, v1.z, v1.w};
        f16x8 hh, ll;
        #pragma unroll
        for (int q = 0; q < 8; ++q) {
            _Float16 th = (_Float16)f[q];
            hh[q] = th;
            ll[q] = (_Float16)((f[q] - (float)th) * 2048.0f);
        }
        *(f16x8*)(hi + (size_t)g * 8) = hh;
        *(f16x8*)(lo + (size_t)g * 8) = ll;
    }
}

// ---------------------------------------------------------------------------
// Phase 1: gi = x @ Wi + bi. Tile 128m x 64n, BK=64, 8 stages DOUBLE-BUFFERED
// (one barrier per stage). LDS [row][72] halfs. grid (24 n fastest, R/128 m).
// ---------------------------------------------------------------------------
__global__ __launch_bounds__(256, 1) void gi_gemm(
    const _Float16* __restrict__ XT_hi, const _Float16* __restrict__ XT_lo,
    const _Float16* __restrict__ WT_hi, const _Float16* __restrict__ WT_lo,
    const float* __restrict__ bi,
    float* __restrict__ gi)
{
    __shared__ __align__(16) _Float16 Ah[2][128 * 72];
    __shared__ __align__(16) _Float16 Al[2][128 * 72];
    __shared__ __align__(16) _Float16 Bh[2][64 * 72];
    __shared__ __align__(16) _Float16 Bl[2][64 * 72];

    const int tid = threadIdx.x;
    const int n0 = blockIdx.x * 64;
    const int m0 = blockIdx.y * 128;
    const int l = tid & 63, w = tid >> 6;
    const int lr = l & 15, lkq = l >> 4, lk = lkq * 8;

    const int aRow[4] = { (tid + 0) >> 3, (tid + 256) >> 3, (tid + 512) >> 3, (tid + 768) >> 3 };
    const int aOff = (tid & 7) * 8;

    f16x8 rAh[4], rAl[4], rBh[2], rBl[2];
    #pragma unroll
    for (int i = 0; i < 4; ++i) {
        const size_t g = (size_t)(m0 + aRow[i]) * 512 + aOff;
        rAh[i] = *(const f16x8*)(XT_hi + g);
        rAl[i] = *(const f16x8*)(XT_lo + g);
    }
    #pragma unroll
    for (int i = 0; i < 2; ++i) {
        const size_t g = (size_t)(n0 + aRow[i]) * 512 + aOff;
        rBh[i] = *(const f16x8*)(WT_hi + g);
        rBl[i] = *(const f16x8*)(WT_lo + g);
    }
    // write stage 0 into buffer 0
    #pragma unroll
    for (int i = 0; i < 4; ++i) {
        *(f16x8*)&Ah[0][aRow[i] * 72 + aOff] = rAh[i];
        *(f16x8*)&Al[0][aRow[i] * 72 + aOff] = rAl[i];
    }
    #pragma unroll
    for (int i = 0; i < 2; ++i) {
        *(f16x8*)&Bh[0][aRow[i] * 72 + aOff] = rBh[i];
        *(f16x8*)&Bl[0][aRow[i] * 72 + aOff] = rBl[i];
    }

    f32x4 am[2][4], acr[2][4];
    #pragma unroll
    for (int fm = 0; fm < 2; ++fm)
        #pragma unroll
        for (int fn = 0; fn < 4; ++fn) {
            am[fm][fn] = (f32x4){0, 0, 0, 0};
            acr[fm][fn] = (f32x4){0, 0, 0, 0};
        }

    for (int s = 0; s < 8; ++s) {
        const int p = s & 1;
        __syncthreads();   // buffer p ready
        if (s < 7) {       // issue next-stage global loads (hide under compute)
            const int k0 = (s + 1) * 64;
            #pragma unroll
            for (int i = 0; i < 4; ++i) {
                const size_t g = (size_t)(m0 + aRow[i]) * 512 + k0 + aOff;
                rAh[i] = *(const f16x8*)(XT_hi + g);
                rAl[i] = *(const f16x8*)(XT_lo + g);
            }
            #pragma unroll
            for (int i = 0; i < 2; ++i) {
                const size_t g = (size_t)(n0 + aRow[i]) * 512 + k0 + aOff;
                rBh[i] = *(const f16x8*)(WT_hi + g);
                rBl[i] = *(const f16x8*)(WT_lo + g);
            }
        }

        #pragma unroll
        for (int kk = 0; kk < 2; ++kk) {
            const int ko = kk * 32 + lk;
            f16x8 ah[2], al[2], bh[4], bl[4];
            #pragma unroll
            for (int fm = 0; fm < 2; ++fm) {
                ah[fm] = *(const f16x8*)&Ah[p][(w * 32 + fm * 16 + lr) * 72 + ko];
                al[fm] = *(const f16x8*)&Al[p][(w * 32 + fm * 16 + lr) * 72 + ko];
            }
            #pragma unroll
            for (int fn = 0; fn < 4; ++fn) {
                bh[fn] = *(const f16x8*)&Bh[p][(fn * 16 + lr) * 72 + ko];
                bl[fn] = *(const f16x8*)&Bl[p][(fn * 16 + lr) * 72 + ko];
            }
            #pragma unroll
            for (int fm = 0; fm < 2; ++fm)
                #pragma unroll
                for (int fn = 0; fn < 4; ++fn) {
                    am[fm][fn]  = MFMA16(ah[fm], bh[fn], am[fm][fn]);
                    acr[fm][fn] = MFMA16(ah[fm], bl[fn], acr[fm][fn]);
                    acr[fm][fn] = MFMA16(al[fm], bh[fn], acr[fm][fn]);
                }
        }

        if (s < 7) {       // write stage s+1 into the other buffer
            const int q = p ^ 1;
            #pragma unroll
            for (int i = 0; i < 4; ++i) {
                *(f16x8*)&Ah[q][aRow[i] * 72 + aOff] = rAh[i];
                *(f16x8*)&Al[q][aRow[i] * 72 + aOff] = rAl[i];
            }
            #pragma unroll
            for (int i = 0; i < 2; ++i) {
                *(f16x8*)&Bh[q][aRow[i] * 72 + aOff] = rBh[i];
                *(f16x8*)&Bl[q][aRow[i] * 72 + aOff] = rBl[i];
            }
        }
    }

    const float inv = 1.0f / 2048.0f;
    #pragma unroll
    for (int fn = 0; fn < 4; ++fn) {
        const int col = n0 + fn * 16 + lr;
        const float bv = bi[col];
        #pragma unroll
        for (int fm = 0; fm < 2; ++fm)
            #pragma unroll
            for (int i = 0; i < 4; ++i) {
                const int row = m0 + w * 32 + fm * 16 + lkq * 4 + i;
                gi[(size_t)row * 1536 + col] =
                    am[fm][fn][i] + acr[fm][fn][i] * inv + bv;
            }
    }
}

// ---------------------------------------------------------------------------
// Phase 2: step kernel (R11 structure + double-buffered stages, 1 barrier/stage).
// Tile 32m x 32j x 3 gates, grid (16 j, 16 m), 4 waves (rh=w>>1, jh=w&1).
// ---------------------------------------------------------------------------
__global__ __launch_bounds__(256, 1) void gru_step_h(
    const int*   __restrict__ rst,      // [B]
    const float* __restrict__ hsrc,     // [B][512]
    const _Float16* __restrict__ WT_hi, // hidden rows at 1536+
    const _Float16* __restrict__ WT_lo,
    const float* __restrict__ gi_t,     // [512][1536] (bi folded in)
    const float* __restrict__ bh_n,     // [512]
    float* __restrict__ hdst,
    float* __restrict__ hT_out)
{
    __shared__ __align__(16) _Float16 Ah[2][32 * 72], Al[2][32 * 72];
    __shared__ __align__(16) _Float16 Bs[2][6][32 * 72];

    const int tid = threadIdx.x;
    const int j0 = blockIdx.x * 32;
    const int m0 = blockIdx.y * 32;
    const int l = tid & 63, w = tid >> 6;
    const int rh = w >> 1, jh = w & 1;
    const int lr = l & 15, lk = (l >> 4) * 8;
    const int lk4 = (l >> 4) * 4;
    const int j = j0 + jh * 16 + lr;

    // ---- prefetch epilogue operands (latency hides under the GEMM) ----
    const int rowbase = m0 + rh * 16 + lk4;
    float gi_pre[3][4], h_pre[4];
    #pragma unroll
    for (int i = 0; i < 4; ++i) {
        const size_t gb = (size_t)(rowbase + i) * 1536 + j;
        gi_pre[0][i] = gi_t[gb];
        gi_pre[1][i] = gi_t[gb + 512];
        gi_pre[2][i] = gi_t[gb + 1024];
        h_pre[i] = hsrc[(size_t)(rowbase + i) * 512 + j];
    }

    const int arow = tid >> 3;       // 0..31
    const int ach  = (tid & 7) * 8;  // 0..56
    const bool am  = (rst[m0 + arow] != 0);
    const float* hrow = hsrc + (size_t)(m0 + arow) * 512 + ach;

    const _Float16* bp[6];
    #pragma unroll
    for (int c = 0; c < 6; ++c) {
        const int sgrp = c >> 1;
        const _Float16* src = (c & 1) ? WT_lo : WT_hi;
        bp[c] = src + (size_t)(1536 + sgrp * 512 + j0 + arow) * 512 + ach;
    }

    f32x4 aRm = {0,0,0,0}, aRc = {0,0,0,0};
    f32x4 aZm = {0,0,0,0}, aZc = {0,0,0,0};
    f32x4 aNm = {0,0,0,0}, aNc = {0,0,0,0};

    // stage-0 regs
    float4 a0 = *(const float4*)(hrow);
    float4 a1 = *(const float4*)(hrow + 4);
    f16x8 wv0 = *(const f16x8*)bp[0];
    f16x8 wv1 = *(const f16x8*)bp[1];
    f16x8 wv2 = *(const f16x8*)bp[2];
    f16x8 wv3 = *(const f16x8*)bp[3];
    f16x8 wv4 = *(const f16x8*)bp[4];
    f16x8 wv5 = *(const f16x8*)bp[5];

    // write stage 0 into buffer 0
    {
        float xf[8] = {a0.x, a0.y, a0.z, a0.w, a1.x, a1.y, a1.z, a1.w};
        f16x8 hh, hl;
        #pragma unroll
        for (int q = 0; q < 8; ++q) {
            float v = am ? 0.0f : xf[q];
            _Float16 th = (_Float16)v;
            hh[q] = th; hl[q] = (_Float16)((v - (float)th) * 2048.0f);
        }
        *(f16x8*)&Ah[0][arow * 72 + ach] = hh;
        *(f16x8*)&Al[0][arow * 72 + ach] = hl;
        *(f16x8*)&Bs[0][0][arow * 72 + ach] = wv0;
        *(f16x8*)&Bs[0][1][arow * 72 + ach] = wv1;
        *(f16x8*)&Bs[0][2][arow * 72 + ach] = wv2;
        *(f16x8*)&Bs[0][3][arow * 72 + ach] = wv3;
        *(f16x8*)&Bs[0][4][arow * 72 + ach] = wv4;
        *(f16x8*)&Bs[0][5][arow * 72 + ach] = wv5;
    }

    for (int s = 0; s < 8; ++s) {
        const int p = s & 1;
        __syncthreads();   // buffer p ready
        if (s < 7) {       // issue next-stage loads (hide under compute)
            const int k0 = (s + 1) * 64;
            a0 = *(const float4*)(hrow + k0);
            a1 = *(const float4*)(hrow + k0 + 4);
            wv0 = *(const f16x8*)(bp[0] + k0);
            wv1 = *(const f16x8*)(bp[1] + k0);
            wv2 = *(const f16x8*)(bp[2] + k0);
            wv3 = *(const f16x8*)(bp[3] + k0);
            wv4 = *(const f16x8*)(bp[4] + k0);
            wv5 = *(const f16x8*)(bp[5] + k0);
        }
        #pragma unroll
        for (int kk = 0; kk < 2; ++kk) {
            const int ko = kk * 32 + lk;
            f16x8 ahf = *(const f16x8*)&Ah[p][(rh * 16 + lr) * 72 + ko];
            f16x8 alf = *(const f16x8*)&Al[p][(rh * 16 + lr) * 72 + ko];
            f16x8 b0 = *(const f16x8*)&Bs[p][0][(jh * 16 + lr) * 72 + ko];
            f16x8 b1 = *(const f16x8*)&Bs[p][1][(jh * 16 + lr) * 72 + ko];
            f16x8 b2 = *(const f16x8*)&Bs[p][2][(jh * 16 + lr) * 72 + ko];
            f16x8 b3 = *(const f16x8*)&Bs[p][3][(jh * 16 + lr) * 72 + ko];
            f16x8 b4 = *(const f16x8*)&Bs[p][4][(jh * 16 + lr) * 72 + ko];
            f16x8 b5 = *(const f16x8*)&Bs[p][5][(jh * 16 + lr) * 72 + ko];
            aRm = MFMA16(ahf, b0, aRm);
            aRc = MFMA16(ahf, b1, aRc);
            aRc = MFMA16(alf, b0, aRc);
            aZm = MFMA16(ahf, b2, aZm);
            aZc = MFMA16(ahf, b3, aZc);
            aZc = MFMA16(alf, b2, aZc);
            aNm = MFMA16(ahf, b4, aNm);
            aNc = MFMA16(ahf, b5, aNc);
            aNc = MFMA16(alf, b4, aNc);
        }
        if (s < 7) {       // write stage s+1 into the other buffer
            const int q = p ^ 1;
            float xf[8] = {a0.x, a0.y, a0.z, a0.w, a1.x, a1.y, a1.z, a1.w};
            f16x8 hh, hl;
            #pragma unroll
            for (int qq = 0; qq < 8; ++qq) {
                float v = am ? 0.0f : xf[qq];
                _Float16 th = (_Float16)v;
                hh[qq] = th; hl[qq] = (_Float16)((v - (float)th) * 2048.0f);
            }
            *(f16x8*)&Ah[q][arow * 72 + ach] = hh;
            *(f16x8*)&Al[q][arow * 72 + ach] = hl;
            *(f16x8*)&Bs[q][0][arow * 72 + ach] = wv0;
            *(f16x8*)&Bs[q][1][arow * 72 + ach] = wv1;
            *(f16x8*)&Bs[q][2][arow * 72 + ach] = wv2;
            *(f16x8*)&Bs[q][3][arow * 72 + ach] = wv3;
            *(f16x8*)&Bs[q][4][arow * 72 + ach] = wv4;
            *(f16x8*)&Bs[q][5][arow * 72 + ach] = wv5;
        }
    }

    const float bhn = bh_n[j];
    const float inv = 1.0f / 2048.0f;
    #pragma unroll
    for (int i = 0; i < 4; ++i) {
        const int row = rowbase + i;
        const bool rm = (rst[row] != 0);
        const float heff = rm ? 0.f : h_pre[i];
        const float R = aRm[i] + aRc[i] * inv;
        const float Z = aZm[i] + aZc[i] * inv;
        const float N = aNm[i] + aNc[i] * inv;
        const float r = sigf_(gi_pre[0][i] + R);
        const float z = sigf_(gi_pre[1][i] + Z);
        const float n = tanhf_(gi_pre[2][i] + r * (N + bhn));
        const float hv = (1.f - z) * n + z * heff;
        hdst[(size_t)row * 512 + j] = hv;
        if (hT_out) hT_out[(size_t)row * 512 + j] = hv;
    }
}

// ---------------------------------------------------------------------------
// Fallback: pure-f32 step kernel (only if d_ws too small).
// ---------------------------------------------------------------------------
constexpr int BM_F = 32, BN_F = 32, BK_F = 32;
constexpr int LDT = BM_F + 4;

__global__ __launch_bounds__(256, 1) void gru_step_f32(
    const float* __restrict__ x, const int* __restrict__ rst,
    const float* __restrict__ h_prev, const float* __restrict__ Wi,
    const float* __restrict__ bi, const float* __restrict__ Wh_rz,
    const float* __restrict__ Wh_n, const float* __restrict__ bh_n,
    float* __restrict__ h_out, float* __restrict__ hT_out)
{
    __shared__ float xs[BK_F][LDT];
    __shared__ float hs[BK_F][LDT];
    __shared__ float wt[6][BK_F][LDT];

    const int tid = threadIdx.x;
    const int bm0 = blockIdx.x * BM_F;
    const int jn0 = blockIdx.y * BN_F;
    const int lrw = tid >> 3;
    const int lcw = (tid & 7) << 2;
    const int ty = tid >> 4, tx = tid & 15;
    const int row0 = 2 * ty, col0 = 2 * tx;

    float aR[2][2] = {{0,0},{0,0}}, aZ[2][2] = {{0,0},{0,0}}, aN[2][2] = {{0,0},{0,0}};
    float hR[2][2] = {{0,0},{0,0}}, hZ[2][2] = {{0,0},{0,0}}, hN[2][2] = {{0,0},{0,0}};

    const int ldrow = bm0 + lrw;
    const bool rmaskld = (rst[ldrow] != 0);
    const float* xrow = x + (size_t)ldrow * 512;
    const float* hrow = h_prev + (size_t)ldrow * 512;

    for (int k0 = 0; k0 < 512; k0 += BK_F) {
        float4 xv = *(const float4*)(xrow + k0 + lcw);
        float4 hv = *(const float4*)(hrow + k0 + lcw);
        if (rmaskld) { hv.x = hv.y = hv.z = hv.w = 0.f; }
        const float* wi_row = Wi + (size_t)(k0 + lrw) * 1536;
        const float* wh_row = Wh_rz + (size_t)(k0 + lrw) * 1024;
        float4 w0v = *(const float4*)(wi_row + jn0 + lcw);
        float4 w1v = *(const float4*)(wi_row + 512 + jn0 + lcw);
        float4 w2v = *(const float4*)(wi_row + 1024 + jn0 + lcw);
        float4 w3v = *(const float4*)(wh_row + jn0 + lcw);
        float4 w4v = *(const float4*)(wh_row + 512 + jn0 + lcw);
        float4 w5v = *(const float4*)(Wh_n + (size_t)(k0 + lrw) * 512 + jn0 + lcw);
        __syncthreads();
        xs[lcw+0][lrw]=xv.x; xs[lcw+1][lrw]=xv.y; xs[lcw+2][lrw]=xv.z; xs[lcw+3][lrw]=xv.w;
        hs[lcw+0][lrw]=hv.x; hs[lcw+1][lrw]=hv.y; hs[lcw+2][lrw]=hv.z; hs[lcw+3][lrw]=hv.w;
        *(float4*)&wt[0][lrw][lcw] = w0v; *(float4*)&wt[1][lrw][lcw] = w1v;
        *(float4*)&wt[2][lrw][lcw] = w2v; *(float4*)&wt[3][lrw][lcw] = w3v;
        *(float4*)&wt[4][lrw][lcw] = w4v; *(float4*)&wt[5][lrw][lcw] = w5v;
        __syncthreads();
        #pragma unroll
        for (int kk = 0; kk < BK_F; ++kk) {
            float2 xa = *(const float2*)&xs[kk][row0];
            float2 ha = *(const float2*)&hs[kk][row0];
            float2 w0 = *(const float2*)&wt[0][kk][col0];
            float2 w1 = *(const float2*)&wt[1][kk][col0];
            float2 w2 = *(const float2*)&wt[2][kk][col0];
            float2 w3 = *(const float2*)&wt[3][kk][col0];
            float2 w4 = *(const float2*)&wt[4][kk][col0];
            float2 w5 = *(const float2*)&wt[5][kk][col0];
            aR[0][0]=fmaf(xa.x,w0.x,aR[0][0]); aR[0][1]=fmaf(xa.x,w0.y,aR[0][1]);
            aR[1][0]=fmaf(xa.y,w0.x,aR[1][0]); aR[1][1]=fmaf(xa.y,w0.y,aR[1][1]);
            aZ[0][0]=fmaf(xa.x,w1.x,aZ[0][0]); aZ[0][1]=fmaf(xa.x,w1.y,aZ[0][1]);
            aZ[1][0]=fmaf(xa.y,w1.x,aZ[1][0]); aZ[1][1]=fmaf(xa.y,w1.y,aZ[1][1]);
            aN[0][0]=fmaf(xa.x,w2.x,aN[0][0]); aN[0][1]=fmaf(xa.x,w2.y,aN[0][1]);
            aN[1][0]=fmaf(xa.y,w2.x,aN[1][0]); aN[1][1]=fmaf(xa.y,w2.y,aN[1][1]);
            hR[0][0]=fmaf(ha.x,w3.x,hR[0][0]); hR[0][1]=fmaf(ha.x,w3.y,hR[0][1]);
            hR[1][0]=fmaf(ha.y,w3.x,hR[1][0]); hR[1][1]=fmaf(ha.y,w3.y,hR[1][1]);
            hZ[0][0]=fmaf(ha.x,w4.x,hZ[0][0]); hZ[0][1]=fmaf(ha.x,w4.y,hZ[0][1]);
            hZ[1][0]=fmaf(ha.y,w4.x,hZ[1][0]); hZ[1][1]=fmaf(ha.y,w4.y,hZ[1][1]);
            hN[0][0]=fmaf(ha.x,w5.x,hN[0][0]); hN[0][1]=fmaf(ha.x,w5.y,hN[0][1]);
            hN[1][0]=fmaf(ha.y,w5.x,hN[1][0]); hN[1][1]=fmaf(ha.y,w5.y,hN[1][1]);
        }
    }
    #pragma unroll
    for (int ii = 0; ii < 2; ++ii) {
        const int b = bm0 + row0 + ii;
        const bool rm = (rst[b] != 0);
        #pragma unroll
        for (int jj = 0; jj < 2; ++jj) {
            const int jn = jn0 + col0 + jj;
            const float heff = rm ? 0.f : h_prev[(size_t)b * 512 + jn];
            const float r = sigf_(aR[ii][jj] + bi[jn] + hR[ii][jj]);
            const float z = sigf_(aZ[ii][jj] + bi[512 + jn] + hZ[ii][jj]);
            const float n = tanhf(aN[ii][jj] + bi[1024 + jn] + r * (hN[ii][jj] + bh_n[jn]));
            const float v = (1.f - z) * n + z * heff;
            h_out[(size_t)b * 512 + jn] = v;
            if (hT_out) hT_out[(size_t)b * 512 + jn] = v;
        }
    }
}

// ---------------------------------------------------------------------------
extern "C" void kernel_launch(void* const* d_in, const int* in_sizes, int n_in,
                              void* d_out, int out_size, void* d_ws, size_t ws_size,
                              hipStream_t stream) {
    const float* h0     = (const float*)d_in[0];
    const float* ins    = (const float*)d_in[1];
    const int*   resets = (const int*)  d_in[2];
    const float* Wi     = (const float*)d_in[3];
    const float* bi     = (const float*)d_in[4];
    const float* Wh_rz  = (const float*)d_in[5];
    const float* Wh_n   = (const float*)d_in[6];
    const float* bh_n   = (const float*)d_in[7];

    float* out = (float*)d_out;
    float* hT  = out;
    float* ys  = out + (size_t)B_SZ * HD;

    const size_t WPLANE = (size_t)3072 * 512;
    const size_t HP     = (size_t)512 * 512;
    const size_t wbytes = WPLANE * 2 * sizeof(_Float16);   // 6.3 MB

    int CH = 0;
    const int cands[8] = {128, 64, 32, 16, 8, 4, 2, 1};
    for (int c = 0; c < 8; ++c) {
        const size_t xt = (size_t)cands[c] * HP * 2 * sizeof(_Float16);
        const size_t gb = (size_t)cands[c] * 512 * 1536 * sizeof(float);
        if (ws_size >= wbytes + xt + gb) { CH = cands[c]; break; }
    }

    if (CH > 0) {
        char* p = (char*)d_ws;
        _Float16* WT_hi = (_Float16*)p;  p += WPLANE * 2;
        _Float16* WT_lo = (_Float16*)p;  p += WPLANE * 2;
        _Float16* XT_hi = (_Float16*)p;  p += (size_t)CH * HP * 2;
        _Float16* XT_lo = (_Float16*)p;  p += (size_t)CH * HP * 2;
        float* gi = (float*)p;

        conv_w<<<dim3(8, 48), 256, 0, stream>>>(Wi, Wh_rz, Wh_n, WT_hi, WT_lo);

        for (int t0 = 0; t0 < T_STEPS; t0 += CH) {
            const int n8 = CH * (int)(HP / 8);
            int sgrid = (n8 + 255) / 256; if (sgrid > 4096) sgrid = 4096;
            fsplit<<<sgrid, 256, 0, stream>>>(
                ins + (size_t)t0 * HP, XT_hi, XT_lo, n8);
            gi_gemm<<<dim3(24, CH * 4), 256, 0, stream>>>(
                XT_hi, XT_lo, WT_hi, WT_lo, bi, gi);
            for (int t = t0; t < t0 + CH; ++t) {
                const float* hp = (t == 0) ? h0 : (ys + (size_t)(t - 1) * HP);
                float* ho = ys + (size_t)t * HP;
                gru_step_h<<<dim3(16, 16), 256, 0, stream>>>(
                    resets + (size_t)t * 512, hp, WT_hi, WT_lo,
                    gi + (size_t)(t - t0) * 512 * 1536,
                    bh_n, ho, (t == T_STEPS - 1) ? hT : nullptr);
            }
        }
    } else {
        dim3 grid(B_SZ / BM_F, HD / BN_F);
        for (int t = 0; t < T_STEPS; ++t) {
            const float* hp = (t == 0) ? h0 : (ys + (size_t)(t - 1) * HP);
            float* ho = ys + (size_t)t * HP;
            gru_step_f32<<<grid, 256, 0, stream>>>(
                ins + (size_t)t * HP, resets + (size_t)t * 512,
                hp, Wi, bi, Wh_rz, Wh_n, bh_n,
                ho, (t == T_STEPS - 1) ? hT : nullptr);
        }
    }
}

// Round 14
// 1737.792 us; speedup vs baseline: 1.1355x; 1.1196x over previous
//
#include <hip/hip_runtime.h>
#include <cmath>

// GRU scan, T=128 B=512 D=H=512, split-f16 MFMA (f32-accurate):
//   v = hi + lo/2048 ; a*b ~= ah*bh + (ah*bl + al*bh)/2048
// Phase 0: conv_w (weights -> K-major split planes in ws).
// Phase 1 per chunk: fsplit(x); gi = x@Wi + bi (round-7 SINGLE-buffered GEMM,
//   202us measured; dbuf variant regressed: 110KB LDS -> 1 block/CU).
// Phase 2: 128 per-step kernels (R13 double-buffered stages, ~10.0us/step):
//   32m x 32j x 3 gates, grid (16,16), 4 waves; h f32->split inline; operands
//   through LDS stride-72; 8 stages, ONE barrier each (dbuf, 73.7KB: still
//   2 blocks/CU capacity), global prefetch post-barrier, LDS write post-compute.
// d_out = [hT (B*H) | ys (T*B*H)]; h_prev for step t read from ys[t-1].

#define T_STEPS 128
#define B_SZ 512
#define HD 512

typedef __attribute__((ext_vector_type(8))) _Float16 f16x8;
typedef __attribute__((ext_vector_type(4))) float f32x4;

#define MFMA16(a, b, c) __builtin_amdgcn_mfma_f32_16x16x32_f16((a), (b), (c), 0, 0, 0)

__device__ __forceinline__ float sigf_(float x) { return 1.0f / (1.0f + __expf(-x)); }
__device__ __forceinline__ float tanhf_(float x) { return 1.0f - 2.0f / (__expf(2.0f * x) + 1.0f); }

// ---------------------------------------------------------------------------
// Phase 0: transpose + split weights. WT[n][k]: n<1536 -> Wi col n;
// n>=1536: m=n-1536, g=m>>9, c=m&511: g<2 -> Wh_rz[k][g*512+c]; g==2 -> Wh_n[k][c]
// ---------------------------------------------------------------------------
__global__ __launch_bounds__(256) void conv_w(
    const float* __restrict__ Wi, const float* __restrict__ Wh_rz,
    const float* __restrict__ Wh_n,
    _Float16* __restrict__ WT_hi, _Float16* __restrict__ WT_lo)
{
    __shared__ float Tl[64][65];
    const int tid = threadIdx.x;
    const int k0 = blockIdx.x * 64;
    const int n0 = blockIdx.y * 64;

    const float* base;
    int stride;
    if (n0 < 1536) { base = Wi + n0; stride = 1536; }
    else {
        int m = n0 - 1536, g = m >> 9, c = m & 511;
        if (g < 2) { base = Wh_rz + g * 512 + c; stride = 1024; }
        else       { base = Wh_n + c;            stride = 512; }
    }

    #pragma unroll
    for (int p = 0; p < 4; ++p) {
        int kr = p * 16 + (tid >> 4);
        int nc = (tid & 15) * 4;
        float4 v = *(const float4*)(base + (size_t)(k0 + kr) * stride + nc);
        Tl[kr][nc + 0] = v.x; Tl[kr][nc + 1] = v.y;
        Tl[kr][nc + 2] = v.z; Tl[kr][nc + 3] = v.w;
    }
    __syncthreads();

    const int nr  = tid >> 2;
    const int kc0 = (tid & 3) * 16;
    f16x8 h0v, h1v, l0v, l1v;
    #pragma unroll
    for (int j = 0; j < 16; ++j) {
        float v = Tl[kc0 + j][nr];
        _Float16 th = (_Float16)v;
        _Float16 tl = (_Float16)((v - (float)th) * 2048.0f);
        if (j < 8) { h0v[j] = th; l0v[j] = tl; }
        else       { h1v[j - 8] = th; l1v[j - 8] = tl; }
    }
    size_t o = (size_t)(n0 + nr) * 512 + k0 + kc0;
    *(f16x8*)(WT_hi + o)     = h0v;
    *(f16x8*)(WT_hi + o + 8) = h1v;
    *(f16x8*)(WT_lo + o)     = l0v;
    *(f16x8*)(WT_lo + o + 8) = l1v;
}

// ---------------------------------------------------------------------------
// fsplit: linear f32 -> split f16 planes. n8 = elems/8.
// ---------------------------------------------------------------------------
__global__ __launch_bounds__(256) void fsplit(
    const float* __restrict__ src,
    _Float16* __restrict__ hi, _Float16* __restrict__ lo, int n8)
{
    const int stride = gridDim.x * 256;
    for (int g = blockIdx.x * 256 + threadIdx.x; g < n8; g += stride) {
        const float* p = src + (size_t)g * 8;
        float4 v0 = *(const float4*)p;
        float4 v1 = *(const float4*)(p + 4);
        float f[8] = {v0.x, v0.y, v0.z, v0.w, v1.x, v1.y, v1.z, v1.w};
        f16x8 hh, ll;
        #pragma unroll
        for (int q = 0; q < 8; ++q) {
            _Float16 th = (_Float16)f[q];
            hh[q] = th;
            ll[q] = (_Float16)((f[q] - (float)th) * 2048.0f);
        }
        *(f16x8*)(hi + (size_t)g * 8) = hh;
        *(f16x8*)(lo + (size_t)g * 8) = ll;
    }
}

// ---------------------------------------------------------------------------
// Phase 1: gi = x @ Wi + bi. Tile 128m x 64n, BK=64, 8 stages, 4 waves.
// SINGLE-buffered LDS [row][72] halfs (55KB -> 2 blocks/CU). Reg-staged plane
// copies; next-stage global prefetch. grid (24 n fastest, R/128 m).
// [round-7 kernel, 202 us measured x4]
// ---------------------------------------------------------------------------
__global__ __launch_bounds__(256, 1) void gi_gemm(
    const _Float16* __restrict__ XT_hi, const _Float16* __restrict__ XT_lo,
    const _Float16* __restrict__ WT_hi, const _Float16* __restrict__ WT_lo,
    const float* __restrict__ bi,
    float* __restrict__ gi)
{
    __shared__ __align__(16) _Float16 Ah[128 * 72];
    __shared__ __align__(16) _Float16 Al[128 * 72];
    __shared__ __align__(16) _Float16 Bh[64 * 72];
    __shared__ __align__(16) _Float16 Bl[64 * 72];

    const int tid = threadIdx.x;
    const int n0 = blockIdx.x * 64;
    const int m0 = blockIdx.y * 128;
    const int l = tid & 63, w = tid >> 6;
    const int lr = l & 15, lkq = l >> 4, lk = lkq * 8;

    const int aRow[4] = { (tid + 0) >> 3, (tid + 256) >> 3, (tid + 512) >> 3, (tid + 768) >> 3 };
    const int aOff = (tid & 7) * 8;

    f16x8 rAh[4], rAl[4], rBh[2], rBl[2];
    #pragma unroll
    for (int i = 0; i < 4; ++i) {
        const size_t g = (size_t)(m0 + aRow[i]) * 512 + aOff;
        rAh[i] = *(const f16x8*)(XT_hi + g);
        rAl[i] = *(const f16x8*)(XT_lo + g);
    }
    #pragma unroll
    for (int i = 0; i < 2; ++i) {
        const size_t g = (size_t)(n0 + aRow[i]) * 512 + aOff;
        rBh[i] = *(const f16x8*)(WT_hi + g);
        rBl[i] = *(const f16x8*)(WT_lo + g);
    }

    f32x4 am[2][4], acr[2][4];
    #pragma unroll
    for (int fm = 0; fm < 2; ++fm)
        #pragma unroll
        for (int fn = 0; fn < 4; ++fn) {
            am[fm][fn] = (f32x4){0, 0, 0, 0};
            acr[fm][fn] = (f32x4){0, 0, 0, 0};
        }

    for (int s = 0; s < 8; ++s) {
        __syncthreads();
        #pragma unroll
        for (int i = 0; i < 4; ++i) {
            *(f16x8*)&Ah[aRow[i] * 72 + aOff] = rAh[i];
            *(f16x8*)&Al[aRow[i] * 72 + aOff] = rAl[i];
        }
        #pragma unroll
        for (int i = 0; i < 2; ++i) {
            *(f16x8*)&Bh[aRow[i] * 72 + aOff] = rBh[i];
            *(f16x8*)&Bl[aRow[i] * 72 + aOff] = rBl[i];
        }
        __syncthreads();

        if (s < 7) {
            const int k0 = (s + 1) * 64;
            #pragma unroll
            for (int i = 0; i < 4; ++i) {
                const size_t g = (size_t)(m0 + aRow[i]) * 512 + k0 + aOff;
                rAh[i] = *(const f16x8*)(XT_hi + g);
                rAl[i] = *(const f16x8*)(XT_lo + g);
            }
            #pragma unroll
            for (int i = 0; i < 2; ++i) {
                const size_t g = (size_t)(n0 + aRow[i]) * 512 + k0 + aOff;
                rBh[i] = *(const f16x8*)(WT_hi + g);
                rBl[i] = *(const f16x8*)(WT_lo + g);
            }
        }

        #pragma unroll
        for (int kk = 0; kk < 2; ++kk) {
            const int ko = kk * 32 + lk;
            f16x8 ah[2], al[2], bh[4], bl[4];
            #pragma unroll
            for (int fm = 0; fm < 2; ++fm) {
                ah[fm] = *(const f16x8*)&Ah[(w * 32 + fm * 16 + lr) * 72 + ko];
                al[fm] = *(const f16x8*)&Al[(w * 32 + fm * 16 + lr) * 72 + ko];
            }
            #pragma unroll
            for (int fn = 0; fn < 4; ++fn) {
                bh[fn] = *(const f16x8*)&Bh[(fn * 16 + lr) * 72 + ko];
                bl[fn] = *(const f16x8*)&Bl[(fn * 16 + lr) * 72 + ko];
            }
            #pragma unroll
            for (int fm = 0; fm < 2; ++fm)
                #pragma unroll
                for (int fn = 0; fn < 4; ++fn) {
                    am[fm][fn]  = MFMA16(ah[fm], bh[fn], am[fm][fn]);
                    acr[fm][fn] = MFMA16(ah[fm], bl[fn], acr[fm][fn]);
                    acr[fm][fn] = MFMA16(al[fm], bh[fn], acr[fm][fn]);
                }
        }
    }

    const float inv = 1.0f / 2048.0f;
    #pragma unroll
    for (int fn = 0; fn < 4; ++fn) {
        const int col = n0 + fn * 16 + lr;
        const float bv = bi[col];
        #pragma unroll
        for (int fm = 0; fm < 2; ++fm)
            #pragma unroll
            for (int i = 0; i < 4; ++i) {
                const int row = m0 + w * 32 + fm * 16 + lkq * 4 + i;
                gi[(size_t)row * 1536 + col] =
                    am[fm][fn][i] + acr[fm][fn][i] * inv + bv;
            }
    }
}

// ---------------------------------------------------------------------------
// Phase 2: step kernel (double-buffered stages, 1 barrier/stage, 73.7KB LDS).
// Tile 32m x 32j x 3 gates, grid (16 j, 16 m), 4 waves (rh=w>>1, jh=w&1).
// ---------------------------------------------------------------------------
__global__ __launch_bounds__(256, 1) void gru_step_h(
    const int*   __restrict__ rst,      // [B]
    const float* __restrict__ hsrc,     // [B][512]
    const _Float16* __restrict__ WT_hi, // hidden rows at 1536+
    const _Float16* __restrict__ WT_lo,
    const float* __restrict__ gi_t,     // [512][1536] (bi folded in)
    const float* __restrict__ bh_n,     // [512]
    float* __restrict__ hdst,
    float* __restrict__ hT_out)
{
    __shared__ __align__(16) _Float16 Ah[2][32 * 72], Al[2][32 * 72];
    __shared__ __align__(16) _Float16 Bs[2][6][32 * 72];

    const int tid = threadIdx.x;
    const int j0 = blockIdx.x * 32;
    const int m0 = blockIdx.y * 32;
    const int l = tid & 63, w = tid >> 6;
    const int rh = w >> 1, jh = w & 1;
    const int lr = l & 15, lk = (l >> 4) * 8;
    const int lk4 = (l >> 4) * 4;
    const int j = j0 + jh * 16 + lr;

    // ---- prefetch epilogue operands (latency hides under the GEMM) ----
    const int rowbase = m0 + rh * 16 + lk4;
    float gi_pre[3][4], h_pre[4];
    #pragma unroll
    for (int i = 0; i < 4; ++i) {
        const size_t gb = (size_t)(rowbase + i) * 1536 + j;
        gi_pre[0][i] = gi_t[gb];
        gi_pre[1][i] = gi_t[gb + 512];
        gi_pre[2][i] = gi_t[gb + 1024];
        h_pre[i] = hsrc[(size_t)(rowbase + i) * 512 + j];
    }

    const int arow = tid >> 3;       // 0..31
    const int ach  = (tid & 7) * 8;  // 0..56
    const bool am  = (rst[m0 + arow] != 0);
    const float* hrow = hsrc + (size_t)(m0 + arow) * 512 + ach;

    const _Float16* bp[6];
    #pragma unroll
    for (int c = 0; c < 6; ++c) {
        const int sgrp = c >> 1;
        const _Float16* src = (c & 1) ? WT_lo : WT_hi;
        bp[c] = src + (size_t)(1536 + sgrp * 512 + j0 + arow) * 512 + ach;
    }

    f32x4 aRm = {0,0,0,0}, aRc = {0,0,0,0};
    f32x4 aZm = {0,0,0,0}, aZc = {0,0,0,0};
    f32x4 aNm = {0,0,0,0}, aNc = {0,0,0,0};

    // stage-0 regs
    float4 a0 = *(const float4*)(hrow);
    float4 a1 = *(const float4*)(hrow + 4);
    f16x8 wv0 = *(const f16x8*)bp[0];
    f16x8 wv1 = *(const f16x8*)bp[1];
    f16x8 wv2 = *(const f16x8*)bp[2];
    f16x8 wv3 = *(const f16x8*)bp[3];
    f16x8 wv4 = *(const f16x8*)bp[4];
    f16x8 wv5 = *(const f16x8*)bp[5];

    // write stage 0 into buffer 0
    {
        float xf[8] = {a0.x, a0.y, a0.z, a0.w, a1.x, a1.y, a1.z, a1.w};
        f16x8 hh, hl;
        #pragma unroll
        for (int q = 0; q < 8; ++q) {
            float v = am ? 0.0f : xf[q];
            _Float16 th = (_Float16)v;
            hh[q] = th; hl[q] = (_Float16)((v - (float)th) * 2048.0f);
        }
        *(f16x8*)&Ah[0][arow * 72 + ach] = hh;
        *(f16x8*)&Al[0][arow * 72 + ach] = hl;
        *(f16x8*)&Bs[0][0][arow * 72 + ach] = wv0;
        *(f16x8*)&Bs[0][1][arow * 72 + ach] = wv1;
        *(f16x8*)&Bs[0][2][arow * 72 + ach] = wv2;
        *(f16x8*)&Bs[0][3][arow * 72 + ach] = wv3;
        *(f16x8*)&Bs[0][4][arow * 72 + ach] = wv4;
        *(f16x8*)&Bs[0][5][arow * 72 + ach] = wv5;
    }

    for (int s = 0; s < 8; ++s) {
        const int p = s & 1;
        __syncthreads();   // buffer p ready
        if (s < 7) {       // issue next-stage loads (hide under compute)
            const int k0 = (s + 1) * 64;
            a0 = *(const float4*)(hrow + k0);
            a1 = *(const float4*)(hrow + k0 + 4);
            wv0 = *(const f16x8*)(bp[0] + k0);
            wv1 = *(const f16x8*)(bp[1] + k0);
            wv2 = *(const f16x8*)(bp[2] + k0);
            wv3 = *(const f16x8*)(bp[3] + k0);
            wv4 = *(const f16x8*)(bp[4] + k0);
            wv5 = *(const f16x8*)(bp[5] + k0);
        }
        #pragma unroll
        for (int kk = 0; kk < 2; ++kk) {
            const int ko = kk * 32 + lk;
            f16x8 ahf = *(const f16x8*)&Ah[p][(rh * 16 + lr) * 72 + ko];
            f16x8 alf = *(const f16x8*)&Al[p][(rh * 16 + lr) * 72 + ko];
            f16x8 b0 = *(const f16x8*)&Bs[p][0][(jh * 16 + lr) * 72 + ko];
            f16x8 b1 = *(const f16x8*)&Bs[p][1][(jh * 16 + lr) * 72 + ko];
            f16x8 b2 = *(const f16x8*)&Bs[p][2][(jh * 16 + lr) * 72 + ko];
            f16x8 b3 = *(const f16x8*)&Bs[p][3][(jh * 16 + lr) * 72 + ko];
            f16x8 b4 = *(const f16x8*)&Bs[p][4][(jh * 16 + lr) * 72 + ko];
            f16x8 b5 = *(const f16x8*)&Bs[p][5][(jh * 16 + lr) * 72 + ko];
            aRm = MFMA16(ahf, b0, aRm);
            aRc = MFMA16(ahf, b1, aRc);
            aRc = MFMA16(alf, b0, aRc);
            aZm = MFMA16(ahf, b2, aZm);
            aZc = MFMA16(ahf, b3, aZc);
            aZc = MFMA16(alf, b2, aZc);
            aNm = MFMA16(ahf, b4, aNm);
            aNc = MFMA16(ahf, b5, aNc);
            aNc = MFMA16(alf, b4, aNc);
        }
        if (s < 7) {       // write stage s+1 into the other buffer
            const int q = p ^ 1;
            float xf[8] = {a0.x, a0.y, a0.z, a0.w, a1.x, a1.y, a1.z, a1.w};
            f16x8 hh, hl;
            #pragma unroll
            for (int qq = 0; qq < 8; ++qq) {
                float v = am ? 0.0f : xf[qq];
                _Float16 th = (_Float16)v;
                hh[qq] = th; hl[qq] = (_Float16)((v - (float)th) * 2048.0f);
            }
            *(f16x8*)&Ah[q][arow * 72 + ach] = hh;
            *(f16x8*)&Al[q][arow * 72 + ach] = hl;
            *(f16x8*)&Bs[q][0][arow * 72 + ach] = wv0;
            *(f16x8*)&Bs[q][1][arow * 72 + ach] = wv1;
            *(f16x8*)&Bs[q][2][arow * 72 + ach] = wv2;
            *(f16x8*)&Bs[q][3][arow * 72 + ach] = wv3;
            *(f16x8*)&Bs[q][4][arow * 72 + ach] = wv4;
            *(f16x8*)&Bs[q][5][arow * 72 + ach] = wv5;
        }
    }

    const float bhn = bh_n[j];
    const float inv = 1.0f / 2048.0f;
    #pragma unroll
    for (int i = 0; i < 4; ++i) {
        const int row = rowbase + i;
        const bool rm = (rst[row] != 0);
        const float heff = rm ? 0.f : h_pre[i];
        const float R = aRm[i] + aRc[i] * inv;
        const float Z = aZm[i] + aZc[i] * inv;
        const float N = aNm[i] + aNc[i] * inv;
        const float r = sigf_(gi_pre[0][i] + R);
        const float z = sigf_(gi_pre[1][i] + Z);
        const float n = tanhf_(gi_pre[2][i] + r * (N + bhn));
        const float hv = (1.f - z) * n + z * heff;
        hdst[(size_t)row * 512 + j] = hv;
        if (hT_out) hT_out[(size_t)row * 512 + j] = hv;
    }
}

// ---------------------------------------------------------------------------
// Fallback: pure-f32 step kernel (only if d_ws too small).
// ---------------------------------------------------------------------------
constexpr int BM_F = 32, BN_F = 32, BK_F = 32;
constexpr int LDT = BM_F + 4;

__global__ __launch_bounds__(256, 1) void gru_step_f32(
    const float* __restrict__ x, const int* __restrict__ rst,
    const float* __restrict__ h_prev, const float* __restrict__ Wi,
    const float* __restrict__ bi, const float* __restrict__ Wh_rz,
    const float* __restrict__ Wh_n, const float* __restrict__ bh_n,
    float* __restrict__ h_out, float* __restrict__ hT_out)
{
    __shared__ float xs[BK_F][LDT];
    __shared__ float hs[BK_F][LDT];
    __shared__ float wt[6][BK_F][LDT];

    const int tid = threadIdx.x;
    const int bm0 = blockIdx.x * BM_F;
    const int jn0 = blockIdx.y * BN_F;
    const int lrw = tid >> 3;
    const int lcw = (tid & 7) << 2;
    const int ty = tid >> 4, tx = tid & 15;
    const int row0 = 2 * ty, col0 = 2 * tx;

    float aR[2][2] = {{0,0},{0,0}}, aZ[2][2] = {{0,0},{0,0}}, aN[2][2] = {{0,0},{0,0}};
    float hR[2][2] = {{0,0},{0,0}}, hZ[2][2] = {{0,0},{0,0}}, hN[2][2] = {{0,0},{0,0}};

    const int ldrow = bm0 + lrw;
    const bool rmaskld = (rst[ldrow] != 0);
    const float* xrow = x + (size_t)ldrow * 512;
    const float* hrow = h_prev + (size_t)ldrow * 512;

    for (int k0 = 0; k0 < 512; k0 += BK_F) {
        float4 xv = *(const float4*)(xrow + k0 + lcw);
        float4 hv = *(const float4*)(hrow + k0 + lcw);
        if (rmaskld) { hv.x = hv.y = hv.z = hv.w = 0.f; }
        const float* wi_row = Wi + (size_t)(k0 + lrw) * 1536;
        const float* wh_row = Wh_rz + (size_t)(k0 + lrw) * 1024;
        float4 w0v = *(const float4*)(wi_row + jn0 + lcw);
        float4 w1v = *(const float4*)(wi_row + 512 + jn0 + lcw);
        float4 w2v = *(const float4*)(wi_row + 1024 + jn0 + lcw);
        float4 w3v = *(const float4*)(wh_row + jn0 + lcw);
        float4 w4v = *(const float4*)(wh_row + 512 + jn0 + lcw);
        float4 w5v = *(const float4*)(Wh_n + (size_t)(k0 + lrw) * 512 + jn0 + lcw);
        __syncthreads();
        xs[lcw+0][lrw]=xv.x; xs[lcw+1][lrw]=xv.y; xs[lcw+2][lrw]=xv.z; xs[lcw+3][lrw]=xv.w;
        hs[lcw+0][lrw]=hv.x; hs[lcw+1][lrw]=hv.y; hs[lcw+2][lrw]=hv.z; hs[lcw+3][lrw]=hv.w;
        *(float4*)&wt[0][lrw][lcw] = w0v; *(float4*)&wt[1][lrw][lcw] = w1v;
        *(float4*)&wt[2][lrw][lcw] = w2v; *(float4*)&wt[3][lrw][lcw] = w3v;
        *(float4*)&wt[4][lrw][lcw] = w4v; *(float4*)&wt[5][lrw][lcw] = w5v;
        __syncthreads();
        #pragma unroll
        for (int kk = 0; kk < BK_F; ++kk) {
            float2 xa = *(const float2*)&xs[kk][row0];
            float2 ha = *(const float2*)&hs[kk][row0];
            float2 w0 = *(const float2*)&wt[0][kk][col0];
            float2 w1 = *(const float2*)&wt[1][kk][col0];
            float2 w2 = *(const float2*)&wt[2][kk][col0];
            float2 w3 = *(const float2*)&wt[3][kk][col0];
            float2 w4 = *(const float2*)&wt[4][kk][col0];
            float2 w5 = *(const float2*)&wt[5][kk][col0];
            aR[0][0]=fmaf(xa.x,w0.x,aR[0][0]); aR[0][1]=fmaf(xa.x,w0.y,aR[0][1]);
            aR[1][0]=fmaf(xa.y,w0.x,aR[1][0]); aR[1][1]=fmaf(xa.y,w0.y,aR[1][1]);
            aZ[0][0]=fmaf(xa.x,w1.x,aZ[0][0]); aZ[0][1]=fmaf(xa.x,w1.y,aZ[0][1]);
            aZ[1][0]=fmaf(xa.y,w1.x,aZ[1][0]); aZ[1][1]=fmaf(xa.y,w1.y,aZ[1][1]);
            aN[0][0]=fmaf(xa.x,w2.x,aN[0][0]); aN[0][1]=fmaf(xa.x,w2.y,aN[0][1]);
            aN[1][0]=fmaf(xa.y,w2.x,aN[1][0]); aN[1][1]=fmaf(xa.y,w2.y,aN[1][1]);
            hR[0][0]=fmaf(ha.x,w3.x,hR[0][0]); hR[0][1]=fmaf(ha.x,w3.y,hR[0][1]);
            hR[1][0]=fmaf(ha.y,w3.x,hR[1][0]); hR[1][1]=fmaf(ha.y,w3.y,hR[1][1]);
            hZ[0][0]=fmaf(ha.x,w4.x,hZ[0][0]); hZ[0][1]=fmaf(ha.x,w4.y,hZ[0][1]);
            hZ[1][0]=fmaf(ha.y,w4.x,hZ[1][0]); hZ[1][1]=fmaf(ha.y,w4.y,hZ[1][1]);
            hN[0][0]=fmaf(ha.x,w5.x,hN[0][0]); hN[0][1]=fmaf(ha.x,w5.y,hN[0][1]);
            hN[1][0]=fmaf(ha.y,w5.x,hN[1][0]); hN[1][1]=fmaf(ha.y,w5.y,hN[1][1]);
        }
    }
    #pragma unroll
    for (int ii = 0; ii < 2; ++ii) {
        const int b = bm0 + row0 + ii;
        const bool rm = (rst[b] != 0);
        #pragma unroll
        for (int jj = 0; jj < 2; ++jj) {
            const int jn = jn0 + col0 + jj;
            const float heff = rm ? 0.f : h_prev[(size_t)b * 512 + jn];
            const float r = sigf_(aR[ii][jj] + bi[jn] + hR[ii][jj]);
            const float z = sigf_(aZ[ii][jj] + bi[512 + jn] + hZ[ii][jj]);
            const float n = tanhf(aN[ii][jj] + bi[1024 + jn] + r * (hN[ii][jj] + bh_n[jn]));
            const float v = (1.f - z) * n + z * heff;
            h_out[(size_t)b * 512 + jn] = v;
            if (hT_out) hT_out[(size_t)b * 512 + jn] = v;
        }
    }
}

// ---------------------------------------------------------------------------
extern "C" void kernel_launch(void* const* d_in, const int* in_sizes, int n_in,
                              void* d_out, int out_size, void* d_ws, size_t ws_size,
                              hipStream_t stream) {
    const float* h0     = (const float*)d_in[0];
    const float* ins    = (const float*)d_in[1];
    const int*   resets = (const int*)  d_in[2];
    const float* Wi     = (const float*)d_in[3];
    const float* bi     = (const float*)d_in[4];
    const float* Wh_rz  = (const float*)d_in[5];
    const float* Wh_n   = (const float*)d_in[6];
    const float* bh_n   = (const float*)d_in[7];

    float* out = (float*)d_out;
    float* hT  = out;
    float* ys  = out + (size_t)B_SZ * HD;

    const size_t WPLANE = (size_t)3072 * 512;
    const size_t HP     = (size_t)512 * 512;
    const size_t wbytes = WPLANE * 2 * sizeof(_Float16);   // 6.3 MB

    int CH = 0;
    const int cands[8] = {128, 64, 32, 16, 8, 4, 2, 1};
    for (int c = 0; c < 8; ++c) {
        const size_t xt = (size_t)cands[c] * HP * 2 * sizeof(_Float16);
        const size_t gb = (size_t)cands[c] * 512 * 1536 * sizeof(float);
        if (ws_size >= wbytes + xt + gb) { CH = cands[c]; break; }
    }

    if (CH > 0) {
        char* p = (char*)d_ws;
        _Float16* WT_hi = (_Float16*)p;  p += WPLANE * 2;
        _Float16* WT_lo = (_Float16*)p;  p += WPLANE * 2;
        _Float16* XT_hi = (_Float16*)p;  p += (size_t)CH * HP * 2;
        _Float16* XT_lo = (_Float16*)p;  p += (size_t)CH * HP * 2;
        float* gi = (float*)p;

        conv_w<<<dim3(8, 48), 256, 0, stream>>>(Wi, Wh_rz, Wh_n, WT_hi, WT_lo);

        for (int t0 = 0; t0 < T_STEPS; t0 += CH) {
            const int n8 = CH * (int)(HP / 8);
            int sgrid = (n8 + 255) / 256; if (sgrid > 4096) sgrid = 4096;
            fsplit<<<sgrid, 256, 0, stream>>>(
                ins + (size_t)t0 * HP, XT_hi, XT_lo, n8);
            gi_gemm<<<dim3(24, CH * 4), 256, 0, stream>>>(
                XT_hi, XT_lo, WT_hi, WT_lo, bi, gi);
            for (int t = t0; t < t0 + CH; ++t) {
                const float* hp = (t == 0) ? h0 : (ys + (size_t)(t - 1) * HP);
                float* ho = ys + (size_t)t * HP;
                gru_step_h<<<dim3(16, 16), 256, 0, stream>>>(
                    resets + (size_t)t * 512, hp, WT_hi, WT_lo,
                    gi + (size_t)(t - t0) * 512 * 1536,
                    bh_n, ho, (t == T_STEPS - 1) ? hT : nullptr);
            }
        }
    } else {
        dim3 grid(B_SZ / BM_F, HD / BN_F);
        for (int t = 0; t < T_STEPS; ++t) {
            const float* hp = (t == 0) ? h0 : (ys + (size_t)(t - 1) * HP);
            float* ho = ys + (size_t)t * HP;
            gru_step_f32<<<grid, 256, 0, stream>>>(
                ins + (size_t)t * HP, resets + (size_t)t * 512,
                hp, Wi, bi, Wh_rz, Wh_n, bh_n,
                ho, (t == T_STEPS - 1) ? hT : nullptr);
        }
    }
}